// Round 10
// baseline (374.966 us; speedup 1.0000x reference)
//
#include <hip/hip_runtime.h>
#include <hip/hip_bf16.h>
#include <stdint.h>

// Problem: N=512, R=4, B=65536, OUT=512
// out = relu(x @ W + b1) @ W2 + b2,  W = krylov_recon(G,H) (512x512)

typedef __attribute__((ext_vector_type(8))) short bf16x8;   // MFMA A/B frag (4 VGPR)
typedef __attribute__((ext_vector_type(4))) float f32x4;    // MFMA C/D frag
typedef __attribute__((ext_vector_type(4))) unsigned int u32x4;

__device__ __forceinline__ unsigned short f2bf(float f) {
  return __builtin_bit_cast(unsigned short, __float2bfloat16(f));
}

// ---------------------------------------------------------------------------
// Kernel 1: W partials.  W[a,b] = sum_i sum_j G[(a-j)&511,i]*sgn(b+j)*H[(b+j)&511,i]
// ---------------------------------------------------------------------------
__global__ void build_w_partials(const float* __restrict__ G, const float* __restrict__ H,
                                 float* __restrict__ Wp) {
  __shared__ float4 Gs[512];
  __shared__ float4 Hs[512];
  const int t = threadIdx.x;  // 256
  const float4* G4 = (const float4*)G;
  const float4* H4 = (const float4*)H;
  for (int i = t; i < 512; i += 256) { Gs[i] = G4[i]; Hs[i] = H4[i]; }
  __syncthreads();

  const int blk  = blockIdx.x;      // 0..255
  const int tile = blk >> 2;
  const int jc   = blk & 3;
  const int a0 = (tile >> 3) << 6;
  const int b0 = (tile & 7) << 6;
  const int ab = a0 + ((t >> 4) << 2);
  const int bb = b0 + ((t & 15) << 2);

  float acc[4][4] = {};
  const int j0 = jc << 7;
  for (int jj = 0; jj < 128; ++jj) {
    const int j = j0 + jj;
    float4 Ga[4], Hb[4];
#pragma unroll
    for (int r = 0; r < 4; ++r) Ga[r] = Gs[(ab + r - j) & 511];
#pragma unroll
    for (int c = 0; c < 4; ++c) {
      const int idx = bb + c + j;
      const float s = (idx >= 512) ? -1.f : 1.f;
      const float4 hv = Hs[idx & 511];
      Hb[c].x = hv.x * s; Hb[c].y = hv.y * s; Hb[c].z = hv.z * s; Hb[c].w = hv.w * s;
    }
#pragma unroll
    for (int r = 0; r < 4; ++r)
#pragma unroll
      for (int c = 0; c < 4; ++c)
        acc[r][c] += Ga[r].x * Hb[c].x + Ga[r].y * Hb[c].y +
                     Ga[r].z * Hb[c].z + Ga[r].w * Hb[c].w;
  }

  float* outp = Wp + (size_t)jc * 262144;
#pragma unroll
  for (int r = 0; r < 4; ++r)
#pragma unroll
    for (int c = 0; c < 4; ++c)
      outp[(size_t)(ab + r) * 512 + (bb + c)] = acc[r][c];
}

// ---------------------------------------------------------------------------
// Kernel 2: reduce 4 partials, store W transposed bf16: Wt[n=b][k=a]
// ---------------------------------------------------------------------------
__global__ void reduce_transpose_w(const float* __restrict__ Wp, unsigned short* __restrict__ Wt) {
  const int idx = blockIdx.x * 256 + threadIdx.x;
  const int b = idx >> 9, a = idx & 511;
  const size_t o = (size_t)a * 512 + b;
  float s = Wp[o] + Wp[o + 262144] + Wp[o + 524288] + Wp[o + 786432];
  Wt[(size_t)b * 512 + a] = f2bf(s);
}

// ---------------------------------------------------------------------------
// Kernel 3: W2 (512x512 f32 [k][n]) -> W2t bf16 [n][k]
// ---------------------------------------------------------------------------
__global__ void transpose_convert_w2(const float* __restrict__ W2, unsigned short* __restrict__ W2t) {
  const int idx = blockIdx.x * 256 + threadIdx.x;
  const int n = idx >> 9, k = idx & 511;
  W2t[(size_t)n * 512 + k] = f2bf(W2[(size_t)k * 512 + n]);
}

// ---------------------------------------------------------------------------
// Direct-register GEMM (staging ablation): C[M x 512] = epi(A @ Bt^T + bias)
// NO LDS, NO barriers, NO waitcnt asm. 128x128 block tile, 256 threads
// (2x2 waves, per-wave 64x64 = 4x4 frags of 16x16x32 bf16 MFMA).
// Rationale (m177 staging=90%; mistake #7): B = Wt/W2t is 512 KB total ->
// L1/L2-resident for all blocks; A = x/h has ZERO intra-block reuse and its
// x4 cross-N-block reuse is L2-served (co-XCD swizzle). LDS staging was
// pure overhead. All frags load global->VGPR; all 16 K-step offsets fold
// into load-immediates; compiler software-pipelines the unrolled loop.
//   AF32 (GEMM1): A = x f32, cvt_pk in-reg; epilogue relu + bf16 store.
//   else  (GEMM2): A = h bf16; epilogue f32 store.
// ---------------------------------------------------------------------------
template <bool AF32>
__global__ __launch_bounds__(256, 3) void gemm_direct(
    const void* __restrict__ Ap, const unsigned short* __restrict__ Bt,
    const float* __restrict__ bias, void* __restrict__ Cp) {
  const int tid  = threadIdx.x;
  const int lane = tid & 63;
  const int w    = tid >> 6;          // 0..3
  const int wm   = w & 1;             // M half (64 rows)
  const int wn   = w >> 1;            // N half (64 cols)
  const int lr   = lane & 15;
  const int lq   = lane >> 4;

  const int bid = (int)blockIdx.x;                 // 2048 blocks
  const int wg  = (bid & 7) * 256 + (bid >> 3);    // XCD-bijective (2048%8==0)
  const int m0  = (wg >> 2) << 7;                  // 512 M-tiles
  const int n0  = (wg & 3) << 7;                   // 4 N-tiles

  float bv[4];
#pragma unroll
  for (int ni = 0; ni < 4; ++ni) bv[ni] = bias[n0 + wn * 64 + ni * 16 + lr];

  // per-lane A-frag row bases: row = m0 + wm*64 + mi*16 + lr, k-offset lq*8 elems
  const char* aRow[4];
#pragma unroll
  for (int mi = 0; mi < 4; ++mi)
    aRow[mi] = (const char*)Ap +
               (size_t)(m0 + wm * 64 + mi * 16 + lr) * (AF32 ? 2048 : 1024) +
               (size_t)lq * (AF32 ? 32 : 16);
  // per-lane B-frag row bases: n = n0 + wn*64 + ni*16 + lr  ([n][k] bf16)
  const char* bRow[4];
#pragma unroll
  for (int ni = 0; ni < 4; ++ni)
    bRow[ni] = (const char*)Bt +
               (size_t)(n0 + wn * 64 + ni * 16 + lr) * 1024 + (size_t)lq * 16;

  f32x4 acc[4][4];
  const f32x4 vz = {0.f, 0.f, 0.f, 0.f};
#pragma unroll
  for (int i = 0; i < 4; ++i)
#pragma unroll
    for (int j = 0; j < 4; ++j) acc[i][j] = vz;

#pragma unroll
  for (int t = 0; t < 16; ++t) {               // BK=32 per step, K=512
    bf16x8 bfr[4];
#pragma unroll
    for (int ni = 0; ni < 4; ++ni)
      bfr[ni] = *(const bf16x8*)(bRow[ni] + t * 64);

    bf16x8 afr[4];
    if constexpr (AF32) {
#pragma unroll
      for (int mi = 0; mi < 4; ++mi) {
        const f32x4 lo = *(const f32x4*)(aRow[mi] + t * 128);
        const f32x4 hi = *(const f32x4*)(aRow[mi] + t * 128 + 16);
        unsigned int w0, w1, w2, w3;   // RNE f32->bf16 pack
        asm("v_cvt_pk_bf16_f32 %0, %1, %2" : "=v"(w0) : "v"(lo.x), "v"(lo.y));
        asm("v_cvt_pk_bf16_f32 %0, %1, %2" : "=v"(w1) : "v"(lo.z), "v"(lo.w));
        asm("v_cvt_pk_bf16_f32 %0, %1, %2" : "=v"(w2) : "v"(hi.x), "v"(hi.y));
        asm("v_cvt_pk_bf16_f32 %0, %1, %2" : "=v"(w3) : "v"(hi.z), "v"(hi.w));
        u32x4 pw = {w0, w1, w2, w3};
        afr[mi] = __builtin_bit_cast(bf16x8, pw);
      }
    } else {
#pragma unroll
      for (int mi = 0; mi < 4; ++mi)
        afr[mi] = *(const bf16x8*)(aRow[mi] + t * 64);
    }

    __builtin_amdgcn_s_setprio(1);
#pragma unroll
    for (int mi = 0; mi < 4; ++mi)
#pragma unroll
      for (int ni = 0; ni < 4; ++ni)
        acc[mi][ni] = __builtin_amdgcn_mfma_f32_16x16x32_bf16(afr[mi], bfr[ni], acc[mi][ni], 0, 0, 0);
    __builtin_amdgcn_s_setprio(0);
  }

  // ---- epilogue: C/D col=lr, row=lq*4+i (verified r2-r9) ----
#pragma unroll
  for (int ni = 0; ni < 4; ++ni) {
    const int gc = n0 + wn * 64 + ni * 16 + lr;
#pragma unroll
    for (int mi = 0; mi < 4; ++mi) {
      const int gr = m0 + wm * 64 + mi * 16 + lq * 4;
      const f32x4 v = acc[mi][ni];
#pragma unroll
      for (int i = 0; i < 4; ++i) {
        const float val = v[i] + bv[ni];
        if constexpr (AF32)
          ((unsigned short*)Cp)[(size_t)(gr + i) * 512 + gc] = f2bf(val > 0.f ? val : 0.f);
        else
          ((float*)Cp)[(size_t)(gr + i) * 512 + gc] = val;
      }
    }
  }
}

// ---------------------------------------------------------------------------
extern "C" void kernel_launch(void* const* d_in, const int* in_sizes, int n_in,
                              void* d_out, int out_size, void* d_ws, size_t ws_size,
                              hipStream_t stream) {
  (void)in_sizes; (void)n_in; (void)out_size; (void)ws_size;
  const float* x  = (const float*)d_in[0];  // (65536, 512)
  const float* G  = (const float*)d_in[1];  // (512, 4)
  const float* H  = (const float*)d_in[2];  // (512, 4)
  const float* b1 = (const float*)d_in[3];  // (512,)
  const float* W2 = (const float*)d_in[4];  // (512, 512)
  const float* b2 = (const float*)d_in[5];  // (512,)
  float* out = (float*)d_out;               // (65536, 512) f32

  char* ws = (char*)d_ws;                                    // ~72.4 MB
  unsigned short* h   = (unsigned short*)ws;                 // 67,108,864 B
  unsigned short* Wt  = (unsigned short*)(ws + 67108864);    //    524,288 B
  unsigned short* W2t = (unsigned short*)(ws + 67633152);    //    524,288 B
  float*          Wp  = (float*)(ws + 68157440);             //  4,194,304 B

  build_w_partials<<<256, 256, 0, stream>>>(G, H, Wp);
  reduce_transpose_w<<<1024, 256, 0, stream>>>(Wp, Wt);
  transpose_convert_w2<<<1024, 256, 0, stream>>>(W2, W2t);
  gemm_direct<true><<<2048, 256, 0, stream>>>((const void*)x, Wt, b1, (void*)h);
  gemm_direct<false><<<2048, 256, 0, stream>>>((const void*)h, W2t, b2, (void*)out);
}